// Round 15
// baseline (90.772 us; speedup 1.0000x reference)
//
#include <hip/hip_runtime.h>

#define NGRAPHS 256
#define DIM     256   // K (input dim)
#define HID     128   // N (hidden dim)
#define GRP     32    // rows per wave-group
#define NPERS   512   // persistent blocks (2 per CU)

typedef __attribute__((ext_vector_type(8))) short bf16x8;
typedef __attribute__((ext_vector_type(4))) float f32x4;

__device__ __forceinline__ ushort f2bf_rne(float f) {
    unsigned u = __float_as_uint(f);
    unsigned r = u + 0x7fffu + ((u >> 16) & 1u);
    return (ushort)(r >> 16);
}
__device__ __forceinline__ float tanh_fast(float x) {
    float e = __expf(2.0f * x);
    return 1.0f - 2.0f * __builtin_amdgcn_rcpf(1.0f + e);
}
// pack two fp32 -> u32 holding 2 bf16 (RNE), elem0 in low half
__device__ __forceinline__ unsigned pack2(float a, float b) {
    unsigned ua = __float_as_uint(a), ub = __float_as_uint(b);
    unsigned ra = ua + 0x7fffu + ((ua >> 16) & 1u);
    unsigned rb = ub + 0x7fffu + ((ub >> 16) & 1u);
    return (ra >> 16) | (rb & 0xffff0000u);
}
__device__ __forceinline__ bf16x8 cvt8h(float4 v0, float4 v1) {
    union { unsigned w[4]; bf16x8 v; } H;
    H.w[0] = pack2(v0.x, v0.y);
    H.w[1] = pack2(v0.z, v0.w);
    H.w[2] = pack2(v1.x, v1.y);
    H.w[3] = pack2(v1.z, v1.w);
    return H.v;
}
// fire-and-forget global->LDS DMA, 16B per lane; lds ptr must be wave-uniform
__device__ __forceinline__ void glds16(const void* g, void* l) {
    __builtin_amdgcn_global_load_lds(
        (const __attribute__((address_space(1))) unsigned int*)g,
        (__attribute__((address_space(3))) unsigned int*)l, 16, 0, 0);
}

// ---------------------------------------------------------------------------
// Prep: w1 [256(k)][128(n)] fp32 -> fragment-major bf16 RNE:
//   w1f[(ks*8+nf)*512 + lane*8 + j], lane = lhi*16+llo,
//   element = w1[ks*32+lhi*8+j][nf*16+llo]     (64 KB total, L2-hot)
// ---------------------------------------------------------------------------
__global__ void k_prep(const float* __restrict__ w1, ushort* __restrict__ w1f)
{
    int idx = blockIdx.x * 256 + threadIdx.x;   // 0..32767, k-major
    int k  = idx >> 7, nn = idx & 127;
    int ks = k >> 5, lhi = (k >> 3) & 3, j = k & 7;
    int nf = nn >> 4, llo = nn & 15;
    int lane = lhi * 16 + llo;
    w1f[(ks * 8 + nf) * 512 + lane * 8 + j] = f2bf_rne(w1[idx]);
}

// ---------------------------------------------------------------------------
// Main (persistent, wave-independent): B staged ONCE per block into LDS
// (the only barrier). Each WAVE then grinds 32-row groups independently:
// A global->reg 2-step prefetch -> 16 MFMA/ks (B from LDS) -> tanh/@w2/exp
// (wave-local shuffle reduce) -> phase-B weighted column sums (T14 early
// loads) -> per-group wsp/wse/wsid. Zero barriers in steady state.
// Deterministic (fixed group->wave assignment, no atomics).
// ---------------------------------------------------------------------------
__global__ __launch_bounds__(256, 2) void k_scores(
    const float* __restrict__ x, const int* __restrict__ batch,
    const ushort* __restrict__ w1f,
    const float* __restrict__ b1, const float* __restrict__ w2,
    const float* __restrict__ b2,
    float* __restrict__ wsp, float* __restrict__ wse, int* __restrict__ wsid,
    int n, int ngrp)
{
    __shared__ __align__(16) ushort bs[DIM * HID];   // 64 KB, read-only after stage
    __shared__ float evw[4][GRP];                    // per-wave evals slice

    const int t    = threadIdx.x;
    const int wid  = t >> 6;
    const int lane = t & 63;
    const int lhi  = lane >> 4;
    const int llo  = lane & 15;

    // ---- stage B once per block: 16 glds16/thread, fragment-major ----
#pragma unroll
    for (int i = 0; i < 16; ++i)
        glds16(w1f + (size_t)(i * 256 + t) * 8,
               (unsigned char*)bs + (i * 256 + wid * 64) * 16);
    asm volatile("s_waitcnt vmcnt(0)" ::: "memory");
    __builtin_amdgcn_s_barrier();      // the ONLY block-wide barrier

    const float b2v = b2[0];
    float b1v[8], w2v[8];
#pragma unroll
    for (int nf = 0; nf < 8; ++nf) {
        b1v[nf] = b1[nf * 16 + llo];
        w2v[nf] = w2[nf * 16 + llo];
    }

    // ---- per-wave group loop (waves fully independent) ----
    for (int gq = blockIdx.x * 4 + wid; gq < ngrp; gq += NPERS * 4) {
        const int r0 = gq * GRP;

        // graph ids + boundary via ballot (no LDS, no barrier)
        int rb = r0 + (lane & 31); if (rb >= n) rb = n - 1;
        int gv = batch[rb];
        int g0 = __shfl(gv, 0, 64);
        unsigned long long mb = __ballot(gv != g0);
        int rtrans = mb ? (((int)__ffsll((long long)mb) - 1) & 31) : GRP;

        // A-fragment rows for this lane (mf=0,1)
        int row0 = r0 + llo;
        int row1 = r0 + 16 + llo;
        if (row0 >= n) row0 = n - 1;
        if (row1 >= n) row1 = n - 1;
        const float* xr0 = x + (size_t)row0 * DIM + lhi * 8;
        const float* xr1 = x + (size_t)row1 * DIM + lhi * 8;

        // A prologue: 2 steps in flight
        float4 pA[2][4];
        pA[0][0] = *(const float4*)(xr0);      pA[0][1] = *(const float4*)(xr0 + 4);
        pA[0][2] = *(const float4*)(xr1);      pA[0][3] = *(const float4*)(xr1 + 4);
        pA[1][0] = *(const float4*)(xr0 + 32); pA[1][1] = *(const float4*)(xr0 + 36);
        pA[1][2] = *(const float4*)(xr1 + 32); pA[1][3] = *(const float4*)(xr1 + 36);
        __builtin_amdgcn_sched_barrier(0);

        f32x4 acc[2][8];
#pragma unroll
        for (int i = 0; i < 2; ++i)
#pragma unroll
            for (int j = 0; j < 8; ++j) acc[i][j] = (f32x4){0.f, 0.f, 0.f, 0.f};

        // barrier-free k-loop: A regs (compiler waits), B from LDS
#pragma unroll
        for (int ks = 0; ks < 8; ++ks) {
            const int cur = ks & 1;
            bf16x8 ah0 = cvt8h(pA[cur][0], pA[cur][1]);
            bf16x8 ah1 = cvt8h(pA[cur][2], pA[cur][3]);
            if (ks + 2 < 8) {
                pA[cur][0] = *(const float4*)(xr0 + (ks + 2) * 32);
                pA[cur][1] = *(const float4*)(xr0 + (ks + 2) * 32 + 4);
                pA[cur][2] = *(const float4*)(xr1 + (ks + 2) * 32);
                pA[cur][3] = *(const float4*)(xr1 + (ks + 2) * 32 + 4);
            }
            __builtin_amdgcn_sched_barrier(0);
#pragma unroll
            for (int nf = 0; nf < 8; ++nf) {
                bf16x8 bh = *(const bf16x8*)&bs[ks * 4096 + nf * 512 + lane * 8];
                acc[0][nf] = __builtin_amdgcn_mfma_f32_16x16x32_bf16(ah0, bh, acc[0][nf], 0, 0, 0);
                acc[1][nf] = __builtin_amdgcn_mfma_f32_16x16x32_bf16(ah1, bh, acc[1][nf], 0, 0, 0);
            }
        }

        // T14: issue phase-B batch 0 (rows r0..r0+15) before the epilogue
        float4 xv0[16];
#pragma unroll
        for (int j = 0; j < 16; ++j) {
            int rsrc = r0 + j;
            if (rsrc >= n) rsrc = n - 1;
            xv0[j] = *(const float4*)(x + (size_t)rsrc * DIM + lane * 4);
        }
        __builtin_amdgcn_sched_barrier(0);

        // epilogue: tanh + dot(w2); C: col=llo+16nf, row=mf*16+lhi*4+rg
        float sc[8];
#pragma unroll
        for (int mf = 0; mf < 2; ++mf)
#pragma unroll
            for (int rg = 0; rg < 4; ++rg) {
                float p = 0.f;
#pragma unroll
                for (int nf = 0; nf < 8; ++nf)
                    p += tanh_fast(acc[mf][nf][rg] + b1v[nf]) * w2v[nf];
                sc[mf * 4 + rg] = p;
            }
#pragma unroll
        for (int off = 1; off < 16; off <<= 1)
#pragma unroll
            for (int q = 0; q < 8; ++q) sc[q] += __shfl_xor(sc[q], off, 64);

        // e values (all 16 llo lanes of an lhi group hold identical sc)
        float e8[8];
#pragma unroll
        for (int mf = 0; mf < 2; ++mf)
#pragma unroll
            for (int rg = 0; rg < 4; ++rg) {
                int row = mf * 16 + lhi * 4 + rg;
                float s = sc[mf * 4 + rg] + b2v;
                e8[mf * 4 + rg] = (r0 + row < n) ? __expf(s) : 0.f;
            }
        if (llo == 0) {
#pragma unroll
            for (int mf = 0; mf < 2; ++mf)
#pragma unroll
                for (int rg = 0; rg < 4; ++rg)
                    evw[wid][mf * 16 + lhi * 4 + rg] = e8[mf * 4 + rg];
        }
        asm volatile("s_waitcnt lgkmcnt(0)" ::: "memory");   // same-wave LDS dep
        __builtin_amdgcn_sched_barrier(0);

        // group exp-sum: per-lane sum + cross-lhi shuffle (deterministic)
        float esum = e8[0] + e8[1] + e8[2] + e8[3] + e8[4] + e8[5] + e8[6] + e8[7];
        float tot = __shfl(esum, 0, 64) + __shfl(esum, 16, 64)
                  + __shfl(esum, 32, 64) + __shfl(esum, 48, 64);
        if (lane == 0) {
            wse[gq]  = tot;
            wsid[gq] = g0;
        }

        // phase B: issue batch 1, accumulate batch 0, then batch 1
        float4 xv1[16];
#pragma unroll
        for (int j = 0; j < 16; ++j) {
            int rsrc = r0 + 16 + j;
            if (rsrc >= n) rsrc = n - 1;
            xv1[j] = *(const float4*)(x + (size_t)rsrc * DIM + lane * 4);
        }
        __builtin_amdgcn_sched_barrier(0);

        float4 a0 = {0.f, 0.f, 0.f, 0.f}, a1 = {0.f, 0.f, 0.f, 0.f};
#pragma unroll
        for (int j = 0; j < 16; ++j) {
            float e = evw[wid][j];
            if (j < rtrans) {
                a0.x = fmaf(e, xv0[j].x, a0.x); a0.y = fmaf(e, xv0[j].y, a0.y);
                a0.z = fmaf(e, xv0[j].z, a0.z); a0.w = fmaf(e, xv0[j].w, a0.w);
            } else {
                a1.x = fmaf(e, xv0[j].x, a1.x); a1.y = fmaf(e, xv0[j].y, a1.y);
                a1.z = fmaf(e, xv0[j].z, a1.z); a1.w = fmaf(e, xv0[j].w, a1.w);
            }
        }
#pragma unroll
        for (int j = 0; j < 16; ++j) {
            float e = evw[wid][16 + j];
            if (16 + j < rtrans) {
                a0.x = fmaf(e, xv1[j].x, a0.x); a0.y = fmaf(e, xv1[j].y, a0.y);
                a0.z = fmaf(e, xv1[j].z, a0.z); a0.w = fmaf(e, xv1[j].w, a0.w);
            } else {
                a1.x = fmaf(e, xv1[j].x, a1.x); a1.y = fmaf(e, xv1[j].y, a1.y);
                a1.z = fmaf(e, xv1[j].z, a1.z); a1.w = fmaf(e, xv1[j].w, a1.w);
            }
        }
        *(float4*)&wsp[(size_t)gq * 512 + lane * 4]       = a0;
        *(float4*)&wsp[(size_t)gq * 512 + 256 + lane * 4] = a1;
    }
}

// ---------------------------------------------------------------------------
// Combine: one block per graph (group granularity = 32 rows)
// ---------------------------------------------------------------------------
__global__ __launch_bounds__(256) void k_combine(
    const int* __restrict__ batch, const float* __restrict__ wsp,
    const float* __restrict__ wse, const int* __restrict__ wsid,
    float* __restrict__ out, int n, int ngrp)
{
    __shared__ float sred[256];
    __shared__ int bounds[2];
    const int g = blockIdx.x;
    const int d = threadIdx.x;

    // global softmax denominator (same order in every block -> bitwise equal)
    float p = 0.f;
    for (int i = d; i < ngrp; i += 256) p += wse[i];
    sred[d] = p;
    __syncthreads();
    for (int s = 128; s; s >>= 1) {
        if (d < s) sred[d] += sred[d + s];
        __syncthreads();
    }
    const float S = sred[0];

    if (d < 2) {
        int v = g + d;
        int lo = 0, hi = n;
        while (lo < hi) { int mid = (lo + hi) >> 1; if (batch[mid] < v) lo = mid + 1; else hi = mid; }
        bounds[d] = lo;
    }
    __syncthreads();

    const int st = bounds[0], en = bounds[1];
    float acc = 0.f;
    if (st < en) {
        for (int bb = st >> 5; bb <= (en - 1) >> 5; ++bb) {   // GRP=32
            int slot = (wsid[bb] == g) ? 0 : 1;
            acc += wsp[(size_t)bb * 512 + slot * 256 + d];
        }
    }
    out[g * 256 + d] = acc / S;
}

// ---------------------------------------------------------------------------
extern "C" void kernel_launch(void* const* d_in, const int* in_sizes, int n_in,
                              void* d_out, int out_size, void* d_ws, size_t ws_size,
                              hipStream_t stream)
{
    const float* x     = (const float*)d_in[0];
    const int*   batch = (const int*)d_in[1];
    const float* w1    = (const float*)d_in[2];
    const float* b1    = (const float*)d_in[3];
    const float* w2    = (const float*)d_in[4];
    const float* b2    = (const float*)d_in[5];
    float* out = (float*)d_out;

    const int n    = in_sizes[1];                 // 200000
    const int ngrp = (n + GRP - 1) / GRP;         // 6250

    // ws layout: w1f fragment-major bf16 (64KB) | wsp | wse | wsid
    ushort* w1f = (ushort*)d_ws;
    float*  wsp = (float*)((char*)d_ws + (size_t)DIM * HID * sizeof(ushort));
    float*  wse = wsp + (size_t)ngrp * 512;
    int*    wsid = (int*)(wse + ngrp);

    k_prep<<<dim3(DIM * HID / 256), dim3(256), 0, stream>>>(w1, w1f);
    k_scores<<<dim3(NPERS), dim3(256), 0, stream>>>(x, batch, w1f,
                                                    b1, w2, b2, wsp, wse, wsid,
                                                    n, ngrp);
    k_combine<<<dim3(NGRAPHS), dim3(256), 0, stream>>>(batch, wsp, wse, wsid,
                                                       out, n, ngrp);
}

// Round 16
// 81.987 us; speedup vs baseline: 1.1072x; 1.1072x over previous
//
#include <hip/hip_runtime.h>

#define NGRAPHS 256
#define DIM     256   // K (input dim)
#define HID     128   // N (hidden dim)
#define TILE    128   // rows per tile
#define NPERS   512   // persistent blocks (2 per CU)

typedef __attribute__((ext_vector_type(8))) short bf16x8;
typedef __attribute__((ext_vector_type(4))) float f32x4;

__device__ __forceinline__ ushort f2bf_rne(float f) {
    unsigned u = __float_as_uint(f);
    unsigned r = u + 0x7fffu + ((u >> 16) & 1u);
    return (ushort)(r >> 16);
}
__device__ __forceinline__ float tanh_fast(float x) {
    float e = __expf(2.0f * x);
    return 1.0f - 2.0f * __builtin_amdgcn_rcpf(1.0f + e);
}
// pack two fp32 -> u32 holding 2 bf16 (RNE), elem0 in low half
__device__ __forceinline__ unsigned pack2(float a, float b) {
    unsigned ua = __float_as_uint(a), ub = __float_as_uint(b);
    unsigned ra = ua + 0x7fffu + ((ua >> 16) & 1u);
    unsigned rb = ub + 0x7fffu + ((ub >> 16) & 1u);
    return (ra >> 16) | (rb & 0xffff0000u);
}
__device__ __forceinline__ bf16x8 cvt8h(float4 v0, float4 v1) {
    union { unsigned w[4]; bf16x8 v; } H;
    H.w[0] = pack2(v0.x, v0.y);
    H.w[1] = pack2(v0.z, v0.w);
    H.w[2] = pack2(v1.x, v1.y);
    H.w[3] = pack2(v1.z, v1.w);
    return H.v;
}
// fire-and-forget global->LDS DMA, 16B per lane; lds ptr must be wave-uniform
__device__ __forceinline__ void glds16(const void* g, void* l) {
    __builtin_amdgcn_global_load_lds(
        (const __attribute__((address_space(1))) unsigned int*)g,
        (__attribute__((address_space(3))) unsigned int*)l, 16, 0, 0);
}

// ---------------------------------------------------------------------------
// Prep: w1 [256(k)][128(n)] fp32 -> fragment-major bf16 RNE:
//   w1f[(ks*8+nf)*512 + lane*8 + j], lane = lhi*16+llo,
//   element = w1[ks*32+lhi*8+j][nf*16+llo]     (64 KB total, L2-hot)
// ---------------------------------------------------------------------------
__global__ void k_prep(const float* __restrict__ w1, ushort* __restrict__ w1f)
{
    int idx = blockIdx.x * 256 + threadIdx.x;   // 0..32767, k-major
    int k  = idx >> 7, nn = idx & 127;
    int ks = k >> 5, lhi = (k >> 3) & 3, j = k & 7;
    int nf = nn >> 4, llo = nn & 15;
    int lane = lhi * 16 + llo;
    w1f[(ks * 8 + nf) * 512 + lane * 8 + j] = f2bf_rne(w1[idx]);
}

// ---------------------------------------------------------------------------
// Main (persistent, R14 structure + deep MLP): B staged ONCE per block into
// LDS; grid-stride over 128-row tiles. A global->reg 4-DEEP prefetch;
// barrier-free MFMA k-loop; ALL 32 phase-B row loads issued before the
// epilogue (32 in flight under tanh). Deterministic.
// ---------------------------------------------------------------------------
__global__ __launch_bounds__(256, 2) void k_scores(
    const float* __restrict__ x, const int* __restrict__ batch,
    const ushort* __restrict__ w1f,
    const float* __restrict__ b1, const float* __restrict__ w2,
    const float* __restrict__ b2,
    float* __restrict__ wsp, float* __restrict__ wse, int* __restrict__ wsid,
    int n, int nblk)
{
    __shared__ __align__(16) ushort bs[DIM * HID];   // 64 KB, live whole kernel
    __shared__ float sred[4][2][DIM];                // 8 KB
    __shared__ float evals[TILE];
    __shared__ int   gid[TILE];
    __shared__ float ep[4];

    const int t    = threadIdx.x;
    const int wid  = t >> 6;
    const int lane = t & 63;
    const int lhi  = lane >> 4;
    const int llo  = lane & 15;

    // ---- stage B once: 16 glds16/thread, linear fragment-major ----
#pragma unroll
    for (int i = 0; i < 16; ++i)
        glds16(w1f + (size_t)(i * 256 + t) * 8,
               (unsigned char*)bs + (i * 256 + wid * 64) * 16);
    asm volatile("s_waitcnt vmcnt(0)" ::: "memory");
    __builtin_amdgcn_s_barrier();      // B visible block-wide, forever

    float b2v = b2[0];
    float b1v[8], w2v[8];
#pragma unroll
    for (int nf = 0; nf < 8; ++nf) {
        b1v[nf] = b1[nf * 16 + llo];
        w2v[nf] = w2[nf * 16 + llo];
    }

    for (int tid = blockIdx.x; tid < nblk; tid += NPERS) {
        const int r0 = tid * TILE;

        if (t < TILE) {
            int r = r0 + t;
            gid[t] = batch[r < n ? r : (n - 1)];
        }

        // A-fragment rows for this lane (mf=0,1)
        int row0 = r0 + wid * 32 + llo;
        int row1 = row0 + 16;
        if (row0 >= n) row0 = n - 1;
        if (row1 >= n) row1 = n - 1;
        const float* xr0 = x + (size_t)row0 * DIM + lhi * 8;
        const float* xr1 = x + (size_t)row1 * DIM + lhi * 8;

        // ---- A prologue: 4 steps (16 loads) in flight ----
        float4 pA[4][4];
#pragma unroll
        for (int s = 0; s < 4; ++s) {
            pA[s][0] = *(const float4*)(xr0 + s * 32);
            pA[s][1] = *(const float4*)(xr0 + s * 32 + 4);
            pA[s][2] = *(const float4*)(xr1 + s * 32);
            pA[s][3] = *(const float4*)(xr1 + s * 32 + 4);
        }
        __builtin_amdgcn_sched_barrier(0);

        f32x4 acc[2][8];
#pragma unroll
        for (int i = 0; i < 2; ++i)
#pragma unroll
            for (int j = 0; j < 8; ++j) acc[i][j] = (f32x4){0.f, 0.f, 0.f, 0.f};

        // ---- barrier-free k-loop: A regs (compiler waits), B from LDS ----
#pragma unroll
        for (int ks = 0; ks < 8; ++ks) {
            const int cur = ks & 3;
            bf16x8 ah0 = cvt8h(pA[cur][0], pA[cur][1]);
            bf16x8 ah1 = cvt8h(pA[cur][2], pA[cur][3]);
            if (ks + 4 < 8) {   // reload consumed bank; static under unroll
                pA[cur][0] = *(const float4*)(xr0 + (ks + 4) * 32);
                pA[cur][1] = *(const float4*)(xr0 + (ks + 4) * 32 + 4);
                pA[cur][2] = *(const float4*)(xr1 + (ks + 4) * 32);
                pA[cur][3] = *(const float4*)(xr1 + (ks + 4) * 32 + 4);
            }
            __builtin_amdgcn_sched_barrier(0);
#pragma unroll
            for (int nf = 0; nf < 8; ++nf) {
                bf16x8 bh = *(const bf16x8*)&bs[ks * 4096 + nf * 512 + lane * 8];
                acc[0][nf] = __builtin_amdgcn_mfma_f32_16x16x32_bf16(ah0, bh, acc[0][nf], 0, 0, 0);
                acc[1][nf] = __builtin_amdgcn_mfma_f32_16x16x32_bf16(ah1, bh, acc[1][nf], 0, 0, 0);
            }
        }

        // ---- deep T14: issue ALL 32 phase-B row loads before the epilogue ----
        float4 xv0[16], xv1[16];
#pragma unroll
        for (int j = 0; j < 16; ++j) {
            int rsrc = r0 + wid * 32 + j;
            if (rsrc >= n) rsrc = n - 1;
            xv0[j] = *(const float4*)(x + (size_t)rsrc * DIM + lane * 4);
        }
#pragma unroll
        for (int j = 0; j < 16; ++j) {
            int rsrc = r0 + wid * 32 + 16 + j;
            if (rsrc >= n) rsrc = n - 1;
            xv1[j] = *(const float4*)(x + (size_t)rsrc * DIM + lane * 4);
        }
        __builtin_amdgcn_sched_barrier(0);

        // ---- epilogue: tanh + dot(w2); C: col=llo+16nf, row=lhi*4+rg ----
        float sc[8];
#pragma unroll
        for (int mf = 0; mf < 2; ++mf)
#pragma unroll
            for (int rg = 0; rg < 4; ++rg) {
                float p = 0.f;
#pragma unroll
                for (int nf = 0; nf < 8; ++nf)
                    p += tanh_fast(acc[mf][nf][rg] + b1v[nf]) * w2v[nf];
                sc[mf * 4 + rg] = p;
            }
#pragma unroll
        for (int off = 1; off < 16; off <<= 1)
#pragma unroll
            for (int q = 0; q < 8; ++q) sc[q] += __shfl_xor(sc[q], off, 64);

        if (llo == 0) {
#pragma unroll
            for (int mf = 0; mf < 2; ++mf)
#pragma unroll
                for (int rg = 0; rg < 4; ++rg) {
                    int row = wid * 32 + mf * 16 + lhi * 4 + rg;
                    float s = sc[mf * 4 + rg] + b2v;
                    evals[row] = (r0 + row < n) ? __expf(s) : 0.f;
                }
        }
        __syncthreads();   // #1: evals + gid visible

        // ---- phase B: accumulate batch 0 then batch 1 (loads long in flight) ----
        {
            const int g0 = gid[0];
            float4 a0 = {0.f, 0.f, 0.f, 0.f}, a1 = {0.f, 0.f, 0.f, 0.f};
#pragma unroll
            for (int j = 0; j < 16; ++j) {
                int row = wid * 32 + j;
                float e = evals[row];
                if (gid[row] != g0) {
                    a1.x = fmaf(e, xv0[j].x, a1.x); a1.y = fmaf(e, xv0[j].y, a1.y);
                    a1.z = fmaf(e, xv0[j].z, a1.z); a1.w = fmaf(e, xv0[j].w, a1.w);
                } else {
                    a0.x = fmaf(e, xv0[j].x, a0.x); a0.y = fmaf(e, xv0[j].y, a0.y);
                    a0.z = fmaf(e, xv0[j].z, a0.z); a0.w = fmaf(e, xv0[j].w, a0.w);
                }
            }
#pragma unroll
            for (int j = 0; j < 16; ++j) {
                int row = wid * 32 + 16 + j;
                float e = evals[row];
                if (gid[row] != g0) {
                    a1.x = fmaf(e, xv1[j].x, a1.x); a1.y = fmaf(e, xv1[j].y, a1.y);
                    a1.z = fmaf(e, xv1[j].z, a1.z); a1.w = fmaf(e, xv1[j].w, a1.w);
                } else {
                    a0.x = fmaf(e, xv1[j].x, a0.x); a0.y = fmaf(e, xv1[j].y, a0.y);
                    a0.z = fmaf(e, xv1[j].z, a0.z); a0.w = fmaf(e, xv1[j].w, a0.w);
                }
            }
            *(float4*)&sred[wid][0][lane * 4] = a0;
            *(float4*)&sred[wid][1][lane * 4] = a1;
        }
        __syncthreads();   // #2: sred complete
        {
            float s0 = sred[0][0][t] + sred[1][0][t] + sred[2][0][t] + sred[3][0][t];
            float s1 = sred[0][1][t] + sred[1][1][t] + sred[2][1][t] + sred[3][1][t];
            wsp[(size_t)tid * 512 + t]       = s0;
            wsp[(size_t)tid * 512 + 256 + t] = s1;
            if (t == 0) wsid[tid] = gid[0];
        }

        // ---- block exp-sum (deterministic) ----
        float rsum = (t < TILE) ? evals[t] : 0.f;
#pragma unroll
        for (int off = 32; off; off >>= 1) rsum += __shfl_down(rsum, off, 64);
        if ((t & 63) == 0) ep[t >> 6] = rsum;
        __syncthreads();   // #3: ep complete; all tile-i shared reads done
        if (t == 0) wse[tid] = ep[0] + ep[1];
    }
}

// ---------------------------------------------------------------------------
// Combine: one block per graph
// ---------------------------------------------------------------------------
__global__ __launch_bounds__(256) void k_combine(
    const int* __restrict__ batch, const float* __restrict__ wsp,
    const float* __restrict__ wse, const int* __restrict__ wsid,
    float* __restrict__ out, int n, int nblk)
{
    __shared__ float sred[256];
    __shared__ int bounds[2];
    const int g = blockIdx.x;
    const int d = threadIdx.x;

    float p = 0.f;
    for (int i = d; i < nblk; i += 256) p += wse[i];
    sred[d] = p;
    __syncthreads();
    for (int s = 128; s; s >>= 1) {
        if (d < s) sred[d] += sred[d + s];
        __syncthreads();
    }
    const float S = sred[0];

    if (d < 2) {
        int v = g + d;
        int lo = 0, hi = n;
        while (lo < hi) { int mid = (lo + hi) >> 1; if (batch[mid] < v) lo = mid + 1; else hi = mid; }
        bounds[d] = lo;
    }
    __syncthreads();

    const int st = bounds[0], en = bounds[1];
    float acc = 0.f;
    if (st < en) {
        for (int bb = st >> 7; bb <= (en - 1) >> 7; ++bb) {   // TILE=128
            int slot = (wsid[bb] == g) ? 0 : 1;
            acc += wsp[(size_t)bb * 512 + slot * 256 + d];
        }
    }
    out[g * 256 + d] = acc / S;
}

// ---------------------------------------------------------------------------
extern "C" void kernel_launch(void* const* d_in, const int* in_sizes, int n_in,
                              void* d_out, int out_size, void* d_ws, size_t ws_size,
                              hipStream_t stream)
{
    const float* x     = (const float*)d_in[0];
    const int*   batch = (const int*)d_in[1];
    const float* w1    = (const float*)d_in[2];
    const float* b1    = (const float*)d_in[3];
    const float* w2    = (const float*)d_in[4];
    const float* b2    = (const float*)d_in[5];
    float* out = (float*)d_out;

    const int n    = in_sizes[1];                 // 200000
    const int nblk = (n + TILE - 1) / TILE;       // 1563

    // ws layout: w1f fragment-major bf16 (64KB) | wsp | wse | wsid
    ushort* w1f = (ushort*)d_ws;
    float*  wsp = (float*)((char*)d_ws + (size_t)DIM * HID * sizeof(ushort));
    float*  wse = wsp + (size_t)nblk * 512;
    int*    wsid = (int*)(wse + nblk);

    k_prep<<<dim3(DIM * HID / 256), dim3(256), 0, stream>>>(w1, w1f);
    k_scores<<<dim3(NPERS), dim3(256), 0, stream>>>(x, batch, w1f,
                                                    b1, w2, b2, wsp, wse, wsid,
                                                    n, nblk);
    k_combine<<<dim3(NGRAPHS), dim3(256), 0, stream>>>(batch, wsp, wse, wsid,
                                                       out, n, nblk);
}

// Round 17
// 79.744 us; speedup vs baseline: 1.1383x; 1.0281x over previous
//
#include <hip/hip_runtime.h>

#define NGRAPHS 256
#define DIM     256   // K (input dim)
#define HID     128   // N (hidden dim)
#define TILE    128   // rows per tile
#define NPERS   512   // persistent blocks (2 per CU)

typedef __attribute__((ext_vector_type(8))) short bf16x8;
typedef __attribute__((ext_vector_type(4))) float f32x4;

__device__ __forceinline__ ushort f2bf_rne(float f) {
    unsigned u = __float_as_uint(f);
    unsigned r = u + 0x7fffu + ((u >> 16) & 1u);
    return (ushort)(r >> 16);
}
__device__ __forceinline__ float tanh_fast(float x) {
    float e = __expf(2.0f * x);
    return 1.0f - 2.0f * __builtin_amdgcn_rcpf(1.0f + e);
}
// pack two fp32 -> u32 holding 2 bf16 (RNE), elem0 in low half
__device__ __forceinline__ unsigned pack2(float a, float b) {
    unsigned ua = __float_as_uint(a), ub = __float_as_uint(b);
    unsigned ra = ua + 0x7fffu + ((ua >> 16) & 1u);
    unsigned rb = ub + 0x7fffu + ((ub >> 16) & 1u);
    return (ra >> 16) | (rb & 0xffff0000u);
}
__device__ __forceinline__ bf16x8 cvt8h(float4 v0, float4 v1) {
    union { unsigned w[4]; bf16x8 v; } H;
    H.w[0] = pack2(v0.x, v0.y);
    H.w[1] = pack2(v0.z, v0.w);
    H.w[2] = pack2(v1.x, v1.y);
    H.w[3] = pack2(v1.z, v1.w);
    return H.v;
}
// fire-and-forget global->LDS DMA, 16B per lane; lds ptr must be wave-uniform
__device__ __forceinline__ void glds16(const void* g, void* l) {
    __builtin_amdgcn_global_load_lds(
        (const __attribute__((address_space(1))) unsigned int*)g,
        (__attribute__((address_space(3))) unsigned int*)l, 16, 0, 0);
}

// ---------------------------------------------------------------------------
// Prep: w1 [256(k)][128(n)] fp32 -> fragment-major bf16 RNE:
//   w1f[(ks*8+nf)*512 + lane*8 + j], lane = lhi*16+llo,
//   element = w1[ks*32+lhi*8+j][nf*16+llo]     (64 KB total, L2-hot)
// ---------------------------------------------------------------------------
__global__ void k_prep(const float* __restrict__ w1, ushort* __restrict__ w1f)
{
    int idx = blockIdx.x * 256 + threadIdx.x;   // 0..32767, k-major
    int k  = idx >> 7, nn = idx & 127;
    int ks = k >> 5, lhi = (k >> 3) & 3, j = k & 7;
    int nf = nn >> 4, llo = nn & 15;
    int lane = lhi * 16 + llo;
    w1f[(ks * 8 + nf) * 512 + lane * 8 + j] = f2bf_rne(w1[idx]);
}

// ---------------------------------------------------------------------------
// Main (persistent): B staged ONCE per block into LDS; grid-stride loop over
// tiles: A global->reg 2-step prefetch, barrier-free MFMA k-loop, T14 early
// phase-B loads, fp32-exact phase B. Deterministic (fixed tile->block
// assignment, no atomics).
// ---------------------------------------------------------------------------
__global__ __launch_bounds__(256, 2) void k_scores(
    const float* __restrict__ x, const int* __restrict__ batch,
    const ushort* __restrict__ w1f,
    const float* __restrict__ b1, const float* __restrict__ w2,
    const float* __restrict__ b2,
    float* __restrict__ wsp, float* __restrict__ wse, int* __restrict__ wsid,
    int n, int nblk)
{
    __shared__ __align__(16) ushort bs[DIM * HID];   // 64 KB, live whole kernel
    __shared__ float sred[4][2][DIM];                // 8 KB
    __shared__ float evals[TILE];
    __shared__ int   gid[TILE];
    __shared__ float ep[4];

    const int t    = threadIdx.x;
    const int wid  = t >> 6;
    const int lane = t & 63;
    const int lhi  = lane >> 4;
    const int llo  = lane & 15;

    // ---- stage B once: 16 glds16/thread, linear fragment-major ----
#pragma unroll
    for (int i = 0; i < 16; ++i)
        glds16(w1f + (size_t)(i * 256 + t) * 8,
               (unsigned char*)bs + (i * 256 + wid * 64) * 16);
    asm volatile("s_waitcnt vmcnt(0)" ::: "memory");
    __builtin_amdgcn_s_barrier();      // B visible block-wide, forever

    float b2v = b2[0];
    float b1v[8], w2v[8];
#pragma unroll
    for (int nf = 0; nf < 8; ++nf) {
        b1v[nf] = b1[nf * 16 + llo];
        w2v[nf] = w2[nf * 16 + llo];
    }

    for (int tid = blockIdx.x; tid < nblk; tid += NPERS) {
        const int r0 = tid * TILE;

        if (t < TILE) {
            int r = r0 + t;
            gid[t] = batch[r < n ? r : (n - 1)];
        }

        // A-fragment rows for this lane (mf=0,1)
        int row0 = r0 + wid * 32 + llo;
        int row1 = row0 + 16;
        if (row0 >= n) row0 = n - 1;
        if (row1 >= n) row1 = n - 1;
        const float* xr0 = x + (size_t)row0 * DIM + lhi * 8;
        const float* xr1 = x + (size_t)row1 * DIM + lhi * 8;

        // ---- A prologue: 2 steps in flight ----
        float4 pA[2][4];
        pA[0][0] = *(const float4*)(xr0);      pA[0][1] = *(const float4*)(xr0 + 4);
        pA[0][2] = *(const float4*)(xr1);      pA[0][3] = *(const float4*)(xr1 + 4);
        pA[1][0] = *(const float4*)(xr0 + 32); pA[1][1] = *(const float4*)(xr0 + 36);
        pA[1][2] = *(const float4*)(xr1 + 32); pA[1][3] = *(const float4*)(xr1 + 36);
        __builtin_amdgcn_sched_barrier(0);

        f32x4 acc[2][8];
#pragma unroll
        for (int i = 0; i < 2; ++i)
#pragma unroll
            for (int j = 0; j < 8; ++j) acc[i][j] = (f32x4){0.f, 0.f, 0.f, 0.f};

        // ---- barrier-free k-loop: A regs (compiler waits), B from LDS ----
#pragma unroll
        for (int ks = 0; ks < 8; ++ks) {
            const int cur = ks & 1;
            bf16x8 ah0 = cvt8h(pA[cur][0], pA[cur][1]);
            bf16x8 ah1 = cvt8h(pA[cur][2], pA[cur][3]);
            if (ks + 2 < 8) {
                pA[cur][0] = *(const float4*)(xr0 + (ks + 2) * 32);
                pA[cur][1] = *(const float4*)(xr0 + (ks + 2) * 32 + 4);
                pA[cur][2] = *(const float4*)(xr1 + (ks + 2) * 32);
                pA[cur][3] = *(const float4*)(xr1 + (ks + 2) * 32 + 4);
            }
            __builtin_amdgcn_sched_barrier(0);
#pragma unroll
            for (int nf = 0; nf < 8; ++nf) {
                bf16x8 bh = *(const bf16x8*)&bs[ks * 4096 + nf * 512 + lane * 8];
                acc[0][nf] = __builtin_amdgcn_mfma_f32_16x16x32_bf16(ah0, bh, acc[0][nf], 0, 0, 0);
                acc[1][nf] = __builtin_amdgcn_mfma_f32_16x16x32_bf16(ah1, bh, acc[1][nf], 0, 0, 0);
            }
        }

        // ---- T14: issue phase-B batch 0 BEFORE epilogue ----
        float4 xv0[16];
#pragma unroll
        for (int j = 0; j < 16; ++j) {
            int rsrc = r0 + wid * 32 + j;
            if (rsrc >= n) rsrc = n - 1;
            xv0[j] = *(const float4*)(x + (size_t)rsrc * DIM + lane * 4);
        }
        __builtin_amdgcn_sched_barrier(0);

        // ---- epilogue: tanh + dot(w2); C: col=llo+16nf, row=lhi*4+rg ----
        float sc[8];
#pragma unroll
        for (int mf = 0; mf < 2; ++mf)
#pragma unroll
            for (int rg = 0; rg < 4; ++rg) {
                float p = 0.f;
#pragma unroll
                for (int nf = 0; nf < 8; ++nf)
                    p += tanh_fast(acc[mf][nf][rg] + b1v[nf]) * w2v[nf];
                sc[mf * 4 + rg] = p;
            }
#pragma unroll
        for (int off = 1; off < 16; off <<= 1)
#pragma unroll
            for (int q = 0; q < 8; ++q) sc[q] += __shfl_xor(sc[q], off, 64);

        if (llo == 0) {
#pragma unroll
            for (int mf = 0; mf < 2; ++mf)
#pragma unroll
                for (int rg = 0; rg < 4; ++rg) {
                    int row = wid * 32 + mf * 16 + lhi * 4 + rg;
                    float s = sc[mf * 4 + rg] + b2v;
                    evals[row] = (r0 + row < n) ? __expf(s) : 0.f;
                }
        }
        __syncthreads();   // #1: evals + gid visible

        // ---- phase B: issue batch 1, accumulate batch 0 then batch 1 ----
        {
            float4 xv1[16];
#pragma unroll
            for (int j = 0; j < 16; ++j) {
                int rsrc = r0 + wid * 32 + 16 + j;
                if (rsrc >= n) rsrc = n - 1;
                xv1[j] = *(const float4*)(x + (size_t)rsrc * DIM + lane * 4);
            }
            __builtin_amdgcn_sched_barrier(0);

            const int g0 = gid[0];
            float4 a0 = {0.f, 0.f, 0.f, 0.f}, a1 = {0.f, 0.f, 0.f, 0.f};
#pragma unroll
            for (int j = 0; j < 16; ++j) {
                int row = wid * 32 + j;
                float e = evals[row];
                if (gid[row] != g0) {
                    a1.x = fmaf(e, xv0[j].x, a1.x); a1.y = fmaf(e, xv0[j].y, a1.y);
                    a1.z = fmaf(e, xv0[j].z, a1.z); a1.w = fmaf(e, xv0[j].w, a1.w);
                } else {
                    a0.x = fmaf(e, xv0[j].x, a0.x); a0.y = fmaf(e, xv0[j].y, a0.y);
                    a0.z = fmaf(e, xv0[j].z, a0.z); a0.w = fmaf(e, xv0[j].w, a0.w);
                }
            }
#pragma unroll
            for (int j = 0; j < 16; ++j) {
                int row = wid * 32 + 16 + j;
                float e = evals[row];
                if (gid[row] != g0) {
                    a1.x = fmaf(e, xv1[j].x, a1.x); a1.y = fmaf(e, xv1[j].y, a1.y);
                    a1.z = fmaf(e, xv1[j].z, a1.z); a1.w = fmaf(e, xv1[j].w, a1.w);
                } else {
                    a0.x = fmaf(e, xv1[j].x, a0.x); a0.y = fmaf(e, xv1[j].y, a0.y);
                    a0.z = fmaf(e, xv1[j].z, a0.z); a0.w = fmaf(e, xv1[j].w, a0.w);
                }
            }
            *(float4*)&sred[wid][0][lane * 4] = a0;
            *(float4*)&sred[wid][1][lane * 4] = a1;
        }
        __syncthreads();   // #2: sred complete
        {
            float s0 = sred[0][0][t] + sred[1][0][t] + sred[2][0][t] + sred[3][0][t];
            float s1 = sred[0][1][t] + sred[1][1][t] + sred[2][1][t] + sred[3][1][t];
            wsp[(size_t)tid * 512 + t]       = s0;
            wsp[(size_t)tid * 512 + 256 + t] = s1;
            if (t == 0) wsid[tid] = gid[0];
        }

        // ---- block exp-sum (deterministic) ----
        float rsum = (t < TILE) ? evals[t] : 0.f;
#pragma unroll
        for (int off = 32; off; off >>= 1) rsum += __shfl_down(rsum, off, 64);
        if ((t & 63) == 0) ep[t >> 6] = rsum;
        __syncthreads();   // #3: ep complete; all tile-i shared reads done
        if (t == 0) wse[tid] = ep[0] + ep[1];
    }
}

// ---------------------------------------------------------------------------
// Combine: one block per graph
// ---------------------------------------------------------------------------
__global__ __launch_bounds__(256) void k_combine(
    const int* __restrict__ batch, const float* __restrict__ wsp,
    const float* __restrict__ wse, const int* __restrict__ wsid,
    float* __restrict__ out, int n, int nblk)
{
    __shared__ float sred[256];
    __shared__ int bounds[2];
    const int g = blockIdx.x;
    const int d = threadIdx.x;

    float p = 0.f;
    for (int i = d; i < nblk; i += 256) p += wse[i];
    sred[d] = p;
    __syncthreads();
    for (int s = 128; s; s >>= 1) {
        if (d < s) sred[d] += sred[d + s];
        __syncthreads();
    }
    const float S = sred[0];

    if (d < 2) {
        int v = g + d;
        int lo = 0, hi = n;
        while (lo < hi) { int mid = (lo + hi) >> 1; if (batch[mid] < v) lo = mid + 1; else hi = mid; }
        bounds[d] = lo;
    }
    __syncthreads();

    const int st = bounds[0], en = bounds[1];
    float acc = 0.f;
    if (st < en) {
        for (int bb = st >> 7; bb <= (en - 1) >> 7; ++bb) {   // TILE=128
            int slot = (wsid[bb] == g) ? 0 : 1;
            acc += wsp[(size_t)bb * 512 + slot * 256 + d];
        }
    }
    out[g * 256 + d] = acc / S;
}

// ---------------------------------------------------------------------------
extern "C" void kernel_launch(void* const* d_in, const int* in_sizes, int n_in,
                              void* d_out, int out_size, void* d_ws, size_t ws_size,
                              hipStream_t stream)
{
    const float* x     = (const float*)d_in[0];
    const int*   batch = (const int*)d_in[1];
    const float* w1    = (const float*)d_in[2];
    const float* b1    = (const float*)d_in[3];
    const float* w2    = (const float*)d_in[4];
    const float* b2    = (const float*)d_in[5];
    float* out = (float*)d_out;

    const int n    = in_sizes[1];                 // 200000
    const int nblk = (n + TILE - 1) / TILE;       // 1563

    // ws layout: w1f fragment-major bf16 (64KB) | wsp | wse | wsid
    ushort* w1f = (ushort*)d_ws;
    float*  wsp = (float*)((char*)d_ws + (size_t)DIM * HID * sizeof(ushort));
    float*  wse = wsp + (size_t)nblk * 512;
    int*    wsid = (int*)(wse + nblk);

    k_prep<<<dim3(DIM * HID / 256), dim3(256), 0, stream>>>(w1, w1f);
    k_scores<<<dim3(NPERS), dim3(256), 0, stream>>>(x, batch, w1f,
                                                    b1, w2, b2, wsp, wse, wsid,
                                                    n, nblk);
    k_combine<<<dim3(NGRAPHS), dim3(256), 0, stream>>>(batch, wsp, wse, wsid,
                                                       out, n, nblk);
}